// Round 1
// baseline (190.203 us; speedup 1.0000x reference)
//
#include <hip/hip_runtime.h>
#include <math.h>

// Problem constants from the reference
constexpr int BS = 64, NC = 16, TS = 200, D = 64;
constexpr int SLAB   = TS * D;        // 12800 contiguous floats per (b,c) cell
constexpr int NSLABS = BS * NC;       // 1024 output cells
// 200 * (0.5 * 64 * log(2*pi)) — total normalization constant per (b,c)
constexpr float LOGNORM_TOTAL = 11762.413225f;

__global__ __launch_bounds__(256)
void Calc_Xi_And_LogLikelihood_71777493451127_kernel(
    const float* __restrict__ mu,
    const float* __restrict__ sigma,
    const float* __restrict__ eps,
    float* __restrict__ xi,
    float* __restrict__ ll)
{
    const int slab = blockIdx.x;                 // one block per (b,c)
    const size_t base = (size_t)slab * SLAB;

    const float4* __restrict__ mu4 = (const float4*)(mu    + base);
    const float4* __restrict__ sg4 = (const float4*)(sigma + base);
    const float4* __restrict__ ep4 = (const float4*)(eps   + base);
    float4* __restrict__ xi4       = (float4*)(xi + base);

    float acc = 0.0f;

    // SLAB/4 = 3200 float4 per block; 256 threads -> 12.5 iterations
    for (int i = threadIdx.x; i < SLAB / 4; i += 256) {
        float4 m = mu4[i];
        float4 s = sg4[i];
        float4 e = ep4[i];
        float4 o;

        // component x
        {
            float sv = s.x + 1e-5f;
            float xv = m.x + sv * e.x;      // xi, same op order as reference
            float zv = (xv - m.x) / sv;     // IEEE div, matches np float32 ref
            acc += -0.5f * zv * zv - __logf(sv);
            o.x = xv;
        }
        // component y
        {
            float sv = s.y + 1e-5f;
            float xv = m.y + sv * e.y;
            float zv = (xv - m.y) / sv;
            acc += -0.5f * zv * zv - __logf(sv);
            o.y = xv;
        }
        // component z
        {
            float sv = s.z + 1e-5f;
            float xv = m.z + sv * e.z;
            float zv = (xv - m.z) / sv;
            acc += -0.5f * zv * zv - __logf(sv);
            o.z = xv;
        }
        // component w
        {
            float sv = s.w + 1e-5f;
            float xv = m.w + sv * e.w;
            float zv = (xv - m.w) / sv;
            acc += -0.5f * zv * zv - __logf(sv);
            o.w = xv;
        }

        xi4[i] = o;
    }

    // Wave-64 shuffle reduction, then cross-wave via LDS (4 waves/block)
    #pragma unroll
    for (int off = 32; off > 0; off >>= 1)
        acc += __shfl_down(acc, off, 64);

    __shared__ float wsum[4];
    const int lane = threadIdx.x & 63;
    const int wid  = threadIdx.x >> 6;
    if (lane == 0) wsum[wid] = acc;
    __syncthreads();

    if (threadIdx.x == 0) {
        float t = wsum[0] + wsum[1] + wsum[2] + wsum[3];
        ll[slab] = t - LOGNORM_TOTAL;
    }
}

extern "C" void kernel_launch(void* const* d_in, const int* in_sizes, int n_in,
                              void* d_out, int out_size, void* d_ws, size_t ws_size,
                              hipStream_t stream) {
    const float* mu    = (const float*)d_in[0];
    const float* sigma = (const float*)d_in[1];
    const float* eps   = (const float*)d_in[2];

    float* xi = (float*)d_out;                       // first output, 13,107,200 floats
    float* ll = (float*)d_out + (size_t)NSLABS * SLAB; // second output, 1024 floats

    Calc_Xi_And_LogLikelihood_71777493451127_kernel<<<NSLABS, 256, 0, stream>>>(
        mu, sigma, eps, xi, ll);
}

// Round 3
// 189.497 us; speedup vs baseline: 1.0037x; 1.0037x over previous
//
#include <hip/hip_runtime.h>
#include <math.h>

// Problem constants from the reference
constexpr int BS = 64, NC = 16, TS = 200, D = 64;
constexpr int SLAB   = TS * D;        // 12800 contiguous floats per (b,c) cell
constexpr int NSLABS = BS * NC;       // 1024 output cells
constexpr int BLOCK  = 512;           // 8 waves/block; 4 blocks/CU -> 32 waves/CU (100% occ)
// 200 * (0.5 * 64 * log(2*pi)) — total normalization constant per (b,c)
constexpr float LOGNORM_TOTAL = 11762.413225f;

// Native clang vector type: works with __builtin_nontemporal_store
typedef float vfloat4 __attribute__((ext_vector_type(4)));

__global__ __launch_bounds__(BLOCK)
void Calc_Xi_And_LogLikelihood_71777493451127_kernel(
    const float* __restrict__ mu,
    const float* __restrict__ sigma,
    const float* __restrict__ eps,
    float* __restrict__ xi,
    float* __restrict__ ll)
{
    const int slab = blockIdx.x;                 // one block per (b,c)
    const size_t base = (size_t)slab * SLAB;

    const vfloat4* __restrict__ mu4 = (const vfloat4*)(mu    + base);
    const vfloat4* __restrict__ sg4 = (const vfloat4*)(sigma + base);
    const vfloat4* __restrict__ ep4 = (const vfloat4*)(eps   + base);
    vfloat4* __restrict__ xi4       = (vfloat4*)(xi + base);

    float acc = 0.0f;

    // SLAB/4 = 3200 float4 per block; 512 threads -> 6.25 iterations
    for (int i = threadIdx.x; i < SLAB / 4; i += BLOCK) {
        vfloat4 s = sg4[i];
        vfloat4 m = mu4[i];
        vfloat4 e = ep4[i];
        vfloat4 o;

        // z = (xi-mu)/s == eps up to rounding noise (<<< tolerance); skip the
        // IEEE divide chain entirely: acc += -0.5*e^2 - log(s)
        float sx = s.x + 1e-5f, sy = s.y + 1e-5f, sz = s.z + 1e-5f, sw = s.w + 1e-5f;

        o.x = fmaf(sx, e.x, m.x);
        o.y = fmaf(sy, e.y, m.y);
        o.z = fmaf(sz, e.z, m.z);
        o.w = fmaf(sw, e.w, m.w);

        acc += -0.5f * e.x * e.x - __logf(sx);
        acc += -0.5f * e.y * e.y - __logf(sy);
        acc += -0.5f * e.z * e.z - __logf(sz);
        acc += -0.5f * e.w * e.w - __logf(sw);

        // xi is write-only: non-temporal store, don't pollute L2/L3
        __builtin_nontemporal_store(o, &xi4[i]);
    }

    // Wave-64 shuffle reduction, then cross-wave via LDS (8 waves/block)
    #pragma unroll
    for (int off = 32; off > 0; off >>= 1)
        acc += __shfl_down(acc, off, 64);

    __shared__ float wsum[BLOCK / 64];
    const int lane = threadIdx.x & 63;
    const int wid  = threadIdx.x >> 6;
    if (lane == 0) wsum[wid] = acc;
    __syncthreads();

    if (threadIdx.x == 0) {
        float t = 0.0f;
        #pragma unroll
        for (int w = 0; w < BLOCK / 64; ++w) t += wsum[w];
        ll[slab] = t - LOGNORM_TOTAL;
    }
}

extern "C" void kernel_launch(void* const* d_in, const int* in_sizes, int n_in,
                              void* d_out, int out_size, void* d_ws, size_t ws_size,
                              hipStream_t stream) {
    const float* mu    = (const float*)d_in[0];
    const float* sigma = (const float*)d_in[1];
    const float* eps   = (const float*)d_in[2];

    float* xi = (float*)d_out;                         // first output, 13,107,200 floats
    float* ll = (float*)d_out + (size_t)NSLABS * SLAB; // second output, 1024 floats

    Calc_Xi_And_LogLikelihood_71777493451127_kernel<<<NSLABS, BLOCK, 0, stream>>>(
        mu, sigma, eps, xi, ll);
}

// Round 4
// 173.128 us; speedup vs baseline: 1.0986x; 1.0945x over previous
//
#include <hip/hip_runtime.h>
#include <math.h>

// Problem constants from the reference
constexpr int BS = 64, NC = 16, TS = 200, D = 64;
constexpr int SLAB   = TS * D;        // 12800 contiguous floats per (b,c) cell
constexpr int NSLABS = BS * NC;       // 1024 output cells
constexpr int BLOCK  = 512;           // 8 waves/block; 4 blocks/CU -> 32 waves/CU
constexpr int NV4    = SLAB / 4;      // 3200 float4 per slab
// 200 * (0.5 * 64 * log(2*pi)) — total normalization constant per (b,c)
constexpr float LOGNORM_TOTAL = 11762.413225f;

// Native clang vector type: works with __builtin_nontemporal_load/store
typedef float vfloat4 __attribute__((ext_vector_type(4)));

__device__ __forceinline__ void body(const vfloat4& s_in, const vfloat4& m,
                                     const vfloat4& e, vfloat4& o,
                                     float& accE, float& accL)
{
    float sx = s_in.x + 1e-5f, sy = s_in.y + 1e-5f,
          sz = s_in.z + 1e-5f, sw = s_in.w + 1e-5f;
    o.x = fmaf(sx, e.x, m.x);
    o.y = fmaf(sy, e.y, m.y);
    o.z = fmaf(sz, e.z, m.z);
    o.w = fmaf(sw, e.w, m.w);
    // z = (xi-mu)/s == eps up to rounding noise (<<< tolerance)
    accE = fmaf(e.x, e.x, accE);
    accE = fmaf(e.y, e.y, accE);
    accE = fmaf(e.z, e.z, accE);
    accE = fmaf(e.w, e.w, accE);
    accL += __logf(sx) + __logf(sy) + __logf(sz) + __logf(sw);
}

__global__ __launch_bounds__(BLOCK)
void Calc_Xi_And_LogLikelihood_71777493451127_kernel(
    const float* __restrict__ mu,
    const float* __restrict__ sigma,
    const float* __restrict__ eps,
    float* __restrict__ xi,
    float* __restrict__ ll)
{
    const int slab = blockIdx.x;                 // one block per (b,c)
    const size_t base = (size_t)slab * SLAB;

    const vfloat4* __restrict__ mu4 = (const vfloat4*)(mu    + base);
    const vfloat4* __restrict__ sg4 = (const vfloat4*)(sigma + base);
    const vfloat4* __restrict__ ep4 = (const vfloat4*)(eps   + base);
    vfloat4* __restrict__ xi4       = (vfloat4*)(xi + base);

    float accE = 0.0f;   // sum of eps^2
    float accL = 0.0f;   // sum of log(s)

    const int tid = threadIdx.x;

    // Main: 3 rounds x 2-wide unroll = 6 full passes of 512 threads (3072 v4)
    #pragma unroll
    for (int k = 0; k < 3; ++k) {
        const int i0 = tid + (2 * k) * BLOCK;
        const int i1 = i0 + BLOCK;
        // batch all 6 loads first (nt: read-once, don't allocate in L2/L3)
        vfloat4 s0 = __builtin_nontemporal_load(&sg4[i0]);
        vfloat4 m0 = __builtin_nontemporal_load(&mu4[i0]);
        vfloat4 e0 = __builtin_nontemporal_load(&ep4[i0]);
        vfloat4 s1 = __builtin_nontemporal_load(&sg4[i1]);
        vfloat4 m1 = __builtin_nontemporal_load(&mu4[i1]);
        vfloat4 e1 = __builtin_nontemporal_load(&ep4[i1]);
        vfloat4 o0, o1;
        body(s0, m0, e0, o0, accE, accL);
        body(s1, m1, e1, o1, accE, accL);
        xi4[i0] = o0;
        xi4[i1] = o1;
    }

    // Tail: 3200 - 3072 = 128 v4 elements
    if (tid < NV4 - 6 * BLOCK) {
        const int i = tid + 6 * BLOCK;
        vfloat4 s = __builtin_nontemporal_load(&sg4[i]);
        vfloat4 m = __builtin_nontemporal_load(&mu4[i]);
        vfloat4 e = __builtin_nontemporal_load(&ep4[i]);
        vfloat4 o;
        body(s, m, e, o, accE, accL);
        xi4[i] = o;
    }

    float acc = -0.5f * accE - accL;

    // Wave-64 shuffle reduction, then cross-wave via LDS (8 waves/block)
    #pragma unroll
    for (int off = 32; off > 0; off >>= 1)
        acc += __shfl_down(acc, off, 64);

    __shared__ float wsum[BLOCK / 64];
    const int lane = tid & 63;
    const int wid  = tid >> 6;
    if (lane == 0) wsum[wid] = acc;
    __syncthreads();

    if (tid == 0) {
        float t = 0.0f;
        #pragma unroll
        for (int w = 0; w < BLOCK / 64; ++w) t += wsum[w];
        ll[slab] = t - LOGNORM_TOTAL;
    }
}

extern "C" void kernel_launch(void* const* d_in, const int* in_sizes, int n_in,
                              void* d_out, int out_size, void* d_ws, size_t ws_size,
                              hipStream_t stream) {
    const float* mu    = (const float*)d_in[0];
    const float* sigma = (const float*)d_in[1];
    const float* eps   = (const float*)d_in[2];

    float* xi = (float*)d_out;                         // first output, 13,107,200 floats
    float* ll = (float*)d_out + (size_t)NSLABS * SLAB; // second output, 1024 floats

    Calc_Xi_And_LogLikelihood_71777493451127_kernel<<<NSLABS, BLOCK, 0, stream>>>(
        mu, sigma, eps, xi, ll);
}

// Round 5
// 169.885 us; speedup vs baseline: 1.1196x; 1.0191x over previous
//
#include <hip/hip_runtime.h>
#include <math.h>

// Problem constants from the reference
constexpr int BS = 64, NC = 16, TS = 200, D = 64;
constexpr int SLAB   = TS * D;        // 12800 contiguous floats per (b,c) cell
constexpr int NSLABS = BS * NC;       // 1024 output cells
constexpr int BLOCK  = 512;           // 8 waves/block
constexpr int NV4    = SLAB / 4;      // 3200 float4 per slab
constexpr int ROUNDS = NV4 / BLOCK;   // 6 full rounds
constexpr int TAILN  = NV4 - ROUNDS * BLOCK;  // 128 leftover v4
// 200 * (0.5 * 64 * log(2*pi)) — total normalization constant per (b,c)
constexpr float LOGNORM_TOTAL = 11762.413225f;

// Native clang vector type: works with __builtin_nontemporal_load/store
typedef float vfloat4 __attribute__((ext_vector_type(4)));

__device__ __forceinline__ void body(const vfloat4& s_in, const vfloat4& m,
                                     const vfloat4& e, vfloat4& o,
                                     float& accE, float& accL)
{
    float sx = s_in.x + 1e-5f, sy = s_in.y + 1e-5f,
          sz = s_in.z + 1e-5f, sw = s_in.w + 1e-5f;
    o.x = fmaf(sx, e.x, m.x);
    o.y = fmaf(sy, e.y, m.y);
    o.z = fmaf(sz, e.z, m.z);
    o.w = fmaf(sw, e.w, m.w);
    // z = (xi-mu)/s == eps up to rounding noise (<<< tolerance)
    accE = fmaf(e.x, e.x, accE);
    accE = fmaf(e.y, e.y, accE);
    accE = fmaf(e.z, e.z, accE);
    accE = fmaf(e.w, e.w, accE);
    accL += __logf(sx) + __logf(sy) + __logf(sz) + __logf(sw);
}

__global__ __launch_bounds__(BLOCK)
void Calc_Xi_And_LogLikelihood_71777493451127_kernel(
    const float* __restrict__ mu,
    const float* __restrict__ sigma,
    const float* __restrict__ eps,
    float* __restrict__ xi,
    float* __restrict__ ll)
{
    const int slab = blockIdx.x;                 // one block per (b,c)
    const size_t base = (size_t)slab * SLAB;

    const vfloat4* __restrict__ mu4 = (const vfloat4*)(mu    + base);
    const vfloat4* __restrict__ sg4 = (const vfloat4*)(sigma + base);
    const vfloat4* __restrict__ ep4 = (const vfloat4*)(eps   + base);
    vfloat4* __restrict__ xi4       = (vfloat4*)(xi + base);

    const int tid = threadIdx.x;
    const bool tail = tid < TAILN;
    const int ti = tid + ROUNDS * BLOCK;

    // ---- Front-load ALL reads: max MLP, grouped by array so each block
    // streams ~48 KB contiguous per array (DRAM row locality), and the
    // read phase is separated from the write phase (fewer R/W turnarounds).
    vfloat4 S[ROUNDS + 1], M[ROUNDS + 1], E[ROUNDS + 1];

    #pragma unroll
    for (int j = 0; j < ROUNDS; ++j)
        S[j] = __builtin_nontemporal_load(&sg4[tid + j * BLOCK]);
    if (tail) S[ROUNDS] = __builtin_nontemporal_load(&sg4[ti]);

    #pragma unroll
    for (int j = 0; j < ROUNDS; ++j)
        M[j] = __builtin_nontemporal_load(&mu4[tid + j * BLOCK]);
    if (tail) M[ROUNDS] = __builtin_nontemporal_load(&mu4[ti]);

    #pragma unroll
    for (int j = 0; j < ROUNDS; ++j)
        E[j] = __builtin_nontemporal_load(&ep4[tid + j * BLOCK]);
    if (tail) E[ROUNDS] = __builtin_nontemporal_load(&ep4[ti]);

    // ---- Compute + store phase
    float accE = 0.0f;   // sum of eps^2
    float accL = 0.0f;   // sum of log(s)

    #pragma unroll
    for (int j = 0; j < ROUNDS; ++j) {
        vfloat4 o;
        body(S[j], M[j], E[j], o, accE, accL);
        __builtin_nontemporal_store(o, &xi4[tid + j * BLOCK]);
    }
    if (tail) {
        vfloat4 o;
        body(S[ROUNDS], M[ROUNDS], E[ROUNDS], o, accE, accL);
        __builtin_nontemporal_store(o, &xi4[ti]);
    }

    float acc = -0.5f * accE - accL;

    // Wave-64 shuffle reduction, then cross-wave via LDS (8 waves/block)
    #pragma unroll
    for (int off = 32; off > 0; off >>= 1)
        acc += __shfl_down(acc, off, 64);

    __shared__ float wsum[BLOCK / 64];
    const int lane = tid & 63;
    const int wid  = tid >> 6;
    if (lane == 0) wsum[wid] = acc;
    __syncthreads();

    if (tid == 0) {
        float t = 0.0f;
        #pragma unroll
        for (int w = 0; w < BLOCK / 64; ++w) t += wsum[w];
        ll[slab] = t - LOGNORM_TOTAL;
    }
}

extern "C" void kernel_launch(void* const* d_in, const int* in_sizes, int n_in,
                              void* d_out, int out_size, void* d_ws, size_t ws_size,
                              hipStream_t stream) {
    const float* mu    = (const float*)d_in[0];
    const float* sigma = (const float*)d_in[1];
    const float* eps   = (const float*)d_in[2];

    float* xi = (float*)d_out;                         // first output, 13,107,200 floats
    float* ll = (float*)d_out + (size_t)NSLABS * SLAB; // second output, 1024 floats

    Calc_Xi_And_LogLikelihood_71777493451127_kernel<<<NSLABS, BLOCK, 0, stream>>>(
        mu, sigma, eps, xi, ll);
}